// Round 18
// baseline (205.910 us; speedup 1.0000x reference)
//
#include <hip/hip_runtime.h>
#include <hip/hip_bf16.h>

// MHA layer. B=4, S=2048, HID=512, H=8, HD=64. fp32 in/out, bf16 MFMA inside.
// R16: qkv_gemm pipeline upgraded to counted-vmcnt (guide T4): 3-buffer LDS
// rotation; per K-step {issue DMA(t+1); s_waitcnt vmcnt(4); raw s_barrier;
// compute(t)}. The t+1 loads stay in flight ACROSS the barrier (never drain
// to 0) - removes the per-step vmcnt(0) stall __syncthreads forces.
// Each wave issues exactly 4 gl16/step -> vmcnt(4) waits only tile-t's own
// loads; barrier then makes all waves' tile-t visible. 3 bufs make the
// buf[(t+1)%3] overwrite safe (last read at compute(t-2), pre-barrier(t-1)).
// LDS 48 KB -> still 3 blocks/CU.
// attn: R14 in-block K-split (54.4 measured). out_gemm: R15 64x64. cvt: R12.

typedef __bf16 v8bf __attribute__((ext_vector_type(8)));
typedef __bf16 v4bf __attribute__((ext_vector_type(4)));
typedef float  v4f  __attribute__((ext_vector_type(4)));

#define MFMA16(a, b, c) __builtin_amdgcn_mfma_f32_16x16x32_bf16((a), (b), (c), 0, 0, 0)

__device__ __forceinline__ void gl16(const __bf16* g, __bf16* l) {
    // DMA 16B/lane global->LDS. LDS dest = wave-uniform base + lane*16.
    __builtin_amdgcn_global_load_lds(
        (const __attribute__((address_space(1))) void*)g,
        (__attribute__((address_space(3))) void*)l, 16, 0, 0);
}

__device__ inline v8bf cvt8(const float* __restrict__ p) {
    const v4f f0 = *(const v4f*)p;
    const v4f f1 = *(const v4f*)(p + 4);
    v8bf r;
    r[0] = (__bf16)f0[0]; r[1] = (__bf16)f0[1]; r[2] = (__bf16)f0[2]; r[3] = (__bf16)f0[3];
    r[4] = (__bf16)f1[0]; r[5] = (__bf16)f1[1]; r[6] = (__bf16)f1[2]; r[7] = (__bf16)f1[3];
    return r;
}

// ---------------------------------------------------------------------------
// K0: fused convert. blocks [0,1024): Wq|Wk|Wv|Wo -> bf16.
//     blocks [1024,7168): xq|xk|xv -> bf16.
// ---------------------------------------------------------------------------
__global__ __launch_bounds__(256) void cvt_all(
    const float* __restrict__ Wq, const float* __restrict__ Wk,
    const float* __restrict__ Wv, const float* __restrict__ Wo,
    const float* __restrict__ xq, const float* __restrict__ xk,
    const float* __restrict__ xv,
    __bf16* __restrict__ Wb, __bf16* __restrict__ xb)
{
    const int bid = blockIdx.x;
    if (bid < 1024) {
        const int idx = (bid * 256 + threadIdx.x) * 4;
        const int w = idx >> 18, off = idx & 262143;
        const float* src = (w == 0) ? Wq : (w == 1) ? Wk : (w == 2) ? Wv : Wo;
        const v4f x = *(const v4f*)(src + off);
        v4bf y;
        y[0] = (__bf16)x[0]; y[1] = (__bf16)x[1]; y[2] = (__bf16)x[2]; y[3] = (__bf16)x[3];
        *(v4bf*)(Wb + idx) = y;
    } else {
        const int idx = ((bid - 1024) * 256 + threadIdx.x) * 8;
        const int w = idx >> 22, off = idx & 4194303;
        const float* src = (w == 0) ? xq : (w == 1) ? xk : xv;
        *(v8bf*)(xb + idx) = cvt8(src + off);
    }
}

// ---------------------------------------------------------------------------
// K1: QKV projection. grid (64, 4, 3), block 256. Tile 128x128, BK=32.
// R16: 3-buffer rotation, counted vmcnt(4), raw s_barrier (see header).
// ---------------------------------------------------------------------------
__global__ __launch_bounds__(256) void qkv_gemm(
    const __bf16* __restrict__ xb, const __bf16* __restrict__ Wb,
    const float* __restrict__ bq, const float* __restrict__ bk, const float* __restrict__ bv,
    __bf16* __restrict__ Qo, __bf16* __restrict__ Ko, __bf16* __restrict__ VTo)
{
    const int z = blockIdx.z;
    const __bf16* x    = xb + (size_t)z * 4194304;
    const __bf16* W    = Wb + (size_t)z * 262144;
    const float*  bias = (z == 0) ? bq : (z == 1) ? bk : bv;

    const int tid = threadIdx.x, wave = tid >> 6, lane = tid & 63;
    const int quad = lane >> 4, r = lane & 15;
    const int wm = wave >> 1, wn = wave & 1;
    const int row0 = blockIdx.x * 128, col0 = blockIdx.y * 128;

    __shared__ __align__(16) __bf16 As[3][4096];   // 24 KB (3 bufs)
    __shared__ __align__(16) __bf16 Bs[3][4096];   // 24 KB

    // Wave stages segs {2*wave, 2*wave+1} of each plane (4 gl16 per step).
    const __bf16* aG[2];
    const __bf16* bG[2];
    int aOff[2];
    for (int j = 0; j < 2; j++) {
        const int s = wave * 2 + j;
        aG[j] = x + (size_t)(row0 + s * 16 + r) * 512 + quad * 8;
        bG[j] = W + (size_t)(col0 + s * 16 + r) * 512 + quad * 8;
        aOff[j] = s * 512;
    }

    v4f acc[4][4] = {};

    // prologue: stage tile 0 -> buf 0 (4 gl16, outstanding = 4)
    for (int j = 0; j < 2; j++) {
        gl16(aG[j], &As[0][aOff[j]]);
        gl16(bG[j], &Bs[0][aOff[j]]);
    }

    int cur = 0, nxt = 1;
    for (int t = 0; t < 16; t++) {
        if (t < 15) {                               // issue t+1 -> buf nxt
            const int kk = (t + 1) * 32;
            for (int j = 0; j < 2; j++) {
                gl16(aG[j] + kk, &As[nxt][aOff[j]]);
                gl16(bG[j] + kk, &Bs[nxt][aOff[j]]);
            }
            // own tile-t loads landed (<=4 outstanding = t+1's)
            asm volatile("s_waitcnt vmcnt(4)" ::: "memory");
        } else {
            asm volatile("s_waitcnt vmcnt(0)" ::: "memory");
        }
        __builtin_amdgcn_s_barrier();               // all waves' tile-t landed
        asm volatile("" ::: "memory");

        v8bf a[4], b[4];
        for (int i = 0; i < 4; i++)
            a[i] = ((const v8bf*)As[cur])[(wm * 4 + i) * 64 + lane];
        for (int i = 0; i < 4; i++)
            b[i] = ((const v8bf*)Bs[cur])[(wn * 4 + i) * 64 + lane];
        for (int mi = 0; mi < 4; mi++)
            for (int ni = 0; ni < 4; ni++)
                acc[mi][ni] = MFMA16(a[mi], b[ni], acc[mi][ni]);

        cur = nxt;
        nxt = (nxt == 2) ? 0 : nxt + 1;
    }

    for (int ni = 0; ni < 4; ni++) {
        const int n = col0 + wn * 64 + ni * 16 + r;
        const float bv_ = bias[n];
        const int hh = n >> 6, hd = n & 63;
        for (int mi = 0; mi < 4; mi++) {
            const int mbase = row0 + wm * 64 + mi * 16 + quad * 4;
            const int bb = mbase >> 11, s0 = mbase & 2047;
            if (z == 2) {
                v4bf pk;
                for (int i = 0; i < 4; i++)
                    pk[i] = (__bf16)(acc[mi][ni][i] + bv_);
                *(v4bf*)&VTo[((size_t)((bb * 8 + hh) * 64 + hd)) * 2048 + s0] = pk;
            } else {
                __bf16* dst = (z == 0) ? Qo : Ko;
                for (int i = 0; i < 4; i++)
                    dst[((size_t)((bb * 8 + hh) * 2048 + s0 + i)) * 64 + hd] =
                        (__bf16)(acc[mi][ni][i] + bv_);
            }
        }
    }
}

// ---------------------------------------------------------------------------
// K2: flash attention, IN-BLOCK K-split (R14, measured 54.4-55.2 us).
// grid (16,32), block 512 (8 waves): waves 0-3 K-half 0, waves 4-7 K-half 1,
// same 128 q. Halves merge via LDS epilogue. LDS 72.5 KB -> 2 blocks/CU.
// ---------------------------------------------------------------------------
__global__ __launch_bounds__(512, 4) void attn(
    const __bf16* __restrict__ Q, const __bf16* __restrict__ K,
    const __bf16* __restrict__ VT, const int* __restrict__ mask,
    __bf16* __restrict__ AO)
{
    // Bijective XCD swizzle: each XCD owns 4 heads (K+V 2 MB < 4 MB L2).
    const int id = blockIdx.y * 16 + blockIdx.x;
    const int x8 = id & 7, j = (id >> 3) & 3, qb = id >> 5;
    const int bh = x8 * 4 + j;
    const int b = bh >> 3, h = bh & 7;
    const int tid = threadIdx.x, wave = tid >> 6, lane = tid & 63;
    const int w4 = wave & 3, half = wave >> 2;
    const int ltid = tid & 255;                 // index within the half
    const int quad = lane >> 4, r = lane & 15;
    const int q0 = qb * 128 + w4 * 32;          // 32 q-rows per wave

    const __bf16* Qb = Q  + (size_t)bh * 2048 * 64;
    const __bf16* Kb = K  + (size_t)bh * 2048 * 64 + (size_t)half * 1024 * 64;
    const __bf16* Vb = VT + (size_t)bh * 64 * 2048 + half * 1024;  // col off
    const int*    mb = mask + (size_t)b * 2048;

    __shared__ __align__(16) __bf16 Kls[2][4096];     // 16 KB (per half)
    __shared__ __align__(16) __bf16 Vls[2][4096];     // 16 KB (per half)
    __shared__ __align__(16) float  biasF[2048];      // 8 KB, all keys
    __shared__ __align__(16) __bf16 PF[8][4][64][8];  // 32 KB frag-major P
    __shared__ float osumX[4][32];                    // 512 B

    for (int i = tid; i < 2048; i += 512)
        biasF[i] = (mb[i] != 0) ? 0.f : -1.0e10f;

    // Staging: each half's 256 threads stage its K/V tile (entries e1,e2).
    const int e1 = ltid, e2 = ltid + 256;
    int seg, l, t_, h_, rr, qd;
    seg = e1 >> 6; l = e1 & 63; t_ = seg >> 1; h_ = seg & 1; rr = l & 15; qd = l >> 4;
    const __bf16* kg1 = Kb + (size_t)(16 * t_ + rr) * 64   + h_ * 32 + qd * 8;
    const __bf16* vg1 = Vb + (size_t)(16 * t_ + rr) * 2048 + h_ * 32 + qd * 8;
    seg = e2 >> 6; l = e2 & 63; t_ = seg >> 1; h_ = seg & 1; rr = l & 15; qd = l >> 4;
    const __bf16* kg2 = Kb + (size_t)(16 * t_ + rr) * 64   + h_ * 32 + qd * 8;
    const __bf16* vg2 = Vb + (size_t)(16 * t_ + rr) * 2048 + h_ * 32 + qd * 8;

    // Q fragments (B-operand), two 16-row groups.
    v8bf qf[2][2];
    for (int g = 0; g < 2; g++) {
        qf[g][0] = *(const v8bf*)(Qb + (size_t)(q0 + g * 16 + r) * 64 +      quad * 8);
        qf[g][1] = *(const v8bf*)(Qb + (size_t)(q0 + g * 16 + r) * 64 + 32 + quad * 8);
    }

    v8bf ones;
    for (int i = 0; i < 8; i++) ones[i] = (__bf16)1.0f;

    v4f o[2][4] = {};
    v4f osum[2] = {};

    const float SC = 0.18033688f;   // 0.125 * log2(e)

    // PF write addressing (MFMA C->A layout bridge).
    const int entE = (quad >> 1) * 16 + r;   // tt even
    const int entO = entE + 32;              // tt odd
    const int eoff = (quad & 1) * 4;

    v8bf ks1 = *(const v8bf*)kg1, ks2 = *(const v8bf*)kg2;   // tile 0 -> regs
    v8bf vs1 = *(const v8bf*)vg1, vs2 = *(const v8bf*)vg2;

    for (int t = 0; t < 16; t++) {
        __syncthreads();                        // prev-tile readers done
        ((v8bf*)Kls[half])[e1] = ks1; ((v8bf*)Kls[half])[e2] = ks2;
        ((v8bf*)Vls[half])[e1] = vs1; ((v8bf*)Vls[half])[e2] = vs2;
        __syncthreads();                        // tile t visible
        if (t < 15) {                           // prefetch t+1 -> regs
            const int k0n = (t + 1) * 64;
            ks1 = *(const v8bf*)(kg1 + (size_t)k0n * 64);
            ks2 = *(const v8bf*)(kg2 + (size_t)k0n * 64);
            vs1 = *(const v8bf*)(vg1 + k0n);
            vs2 = *(const v8bf*)(vg2 + k0n);
        }
        const int k0 = t * 64;                  // local key base in half

        // ---- S^T = K.Q^T : each K fragment feeds both q-groups.
        v4f sa[2][4] = {};
        for (int tt = 0; tt < 4; tt++) {
            const v8bf kf0 = ((const v8bf*)Kls[half])[(tt * 2 + 0) * 64 + lane];
            const v8bf kf1 = ((const v8bf*)Kls[half])[(tt * 2 + 1) * 64 + lane];
            sa[0][tt] = MFMA16(kf0, qf[0][0], sa[0][tt]);
            sa[0][tt] = MFMA16(kf1, qf[0][1], sa[0][tt]);
            sa[1][tt] = MFMA16(kf0, qf[1][0], sa[1][tt]);
            sa[1][tt] = MFMA16(kf1, qf[1][1], sa[1][tt]);
        }

        // ---- p = exp2(s*SC + bias); write fragment-major.
        for (int tt = 0; tt < 4; tt++) {
            const v4f bl = *(const v4f*)&biasF[half * 1024 + k0 + tt * 16 + quad * 4];
            const int ent = (tt & 1) ? entO : entE;
            const int pl = tt >> 1;
            for (int g = 0; g < 2; g++) {
                v4bf pk;
                for (int i = 0; i < 4; i++) {
                    const float p = __builtin_amdgcn_exp2f(fmaf(sa[g][tt][i], SC, bl[i]));
                    pk[i] = (__bf16)p;
                }
                *(v4bf*)&PF[wave][g * 2 + pl][ent][eoff] = pk;
            }
        }
        asm volatile("s_waitcnt lgkmcnt(0)" ::: "memory");  // same-wave cross-lane
        v8bf pa[2][2];
        for (int g = 0; g < 2; g++) {
            pa[g][0] = *(const v8bf*)&PF[wave][g * 2 + 0][lane][0];
            pa[g][1] = *(const v8bf*)&PF[wave][g * 2 + 1][lane][0];
        }

        // ---- row sums on the matrix pipe
        osum[0] = MFMA16(pa[0][0], ones, osum[0]);
        osum[0] = MFMA16(pa[0][1], ones, osum[0]);
        osum[1] = MFMA16(pa[1][0], ones, osum[1]);
        osum[1] = MFMA16(pa[1][1], ones, osum[1]);

        // ---- O += P @ V
        for (int t2 = 0; t2 < 4; t2++) {
            const v8bf vf0 = ((const v8bf*)Vls[half])[(t2 * 2 + 0) * 64 + lane];
            const v8bf vf1 = ((const v8bf*)Vls[half])[(t2 * 2 + 1) * 64 + lane];
            o[0][t2] = MFMA16(pa[0][0], vf0, o[0][t2]);
            o[0][t2] = MFMA16(pa[0][1], vf1, o[0][t2]);
            o[1][t2] = MFMA16(pa[1][0], vf0, o[1][t2]);
            o[1][t2] = MFMA16(pa[1][1], vf1, o[1][t2]);
        }
    }

    // ---- epilogue: merge halves via LDS (PF reused as f32 exchange).
    __syncthreads();                            // all waves done reading PF
    float* ex = (float*)&PF[0][0][0][0];
    if (half == 1) {
        for (int g = 0; g < 2; g++) {
            for (int t2 = 0; t2 < 4; t2++)
                for (int i = 0; i < 4; i++)
                    ex[(w4 * 32 + g * 16 + quad * 4 + i) * 64 + t2 * 16 + r] =
                        o[g][t2][i];
            if (r == 0)
                for (int i = 0; i < 4; i++)
                    osumX[w4][g * 16 + quad * 4 + i] = osum[g][i];
        }
    }
    __syncthreads();                            // exchange visible
    if (half == 0) {
        for (int g = 0; g < 2; g++) {
            float inv[4];
            for (int i = 0; i < 4; i++)
                inv[i] = 1.0f / (osum[g][i] + osumX[w4][g * 16 + quad * 4 + i]);
            for (int t2 = 0; t2 < 4; t2++) {
                const int hd = t2 * 16 + r;
                for (int i = 0; i < 4; i++) {
                    const int s = q0 + g * 16 + quad * 4 + i;
                    const float val = o[g][t2][i] +
                        ex[(w4 * 32 + g * 16 + quad * 4 + i) * 64 + hd];
                    AO[((size_t)b * 2048 + s) * 512 + h * 64 + hd] =
                        (__bf16)(val * inv[i]);
                }
            }
        }
    }
}

// ---------------------------------------------------------------------------
// K3: output projection (R15). Tile 64x64, grid (128, 8) = 1024 blocks =
// 4 blocks/CU = 16 waves/CU. BK=32, 2-phase dbuf DMA. Wave computes 32x32.
// ---------------------------------------------------------------------------
__global__ __launch_bounds__(256) void out_gemm(
    const __bf16* __restrict__ Ai, const __bf16* __restrict__ W,
    const float* __restrict__ bias, float* __restrict__ y)
{
    const int tid = threadIdx.x, wave = tid >> 6, lane = tid & 63;
    const int quad = lane >> 4, r = lane & 15;
    const int wm = wave >> 1, wn = wave & 1;
    const int row0 = blockIdx.x * 64, col0 = blockIdx.y * 64;

    __shared__ __align__(16) __bf16 As[2][2048];   // 64x32 per buf
    __shared__ __align__(16) __bf16 Bs[2][2048];   // 64x32 per buf

    const __bf16* aG = Ai + (size_t)(row0 + wave * 16 + r) * 512 + quad * 8;
    const __bf16* bG = W  + (size_t)(col0 + wave * 16 + r) * 512 + quad * 8;
    const int sOff = wave * 512;

    v4f acc[2][2] = {};

    gl16(aG, &As[0][sOff]);
    gl16(bG, &Bs[0][sOff]);
    __syncthreads();

    for (int t = 0; t < 16; t++) {
        const int cur = t & 1;
        if (t < 15) {
            const int kk = (t + 1) * 32;
            gl16(aG + kk, &As[cur ^ 1][sOff]);
            gl16(bG + kk, &Bs[cur ^ 1][sOff]);
        }
        v8bf a[2], b[2];
        for (int i = 0; i < 2; i++)
            a[i] = ((const v8bf*)As[cur])[(wm * 2 + i) * 64 + lane];
        for (int i = 0; i < 2; i++)
            b[i] = ((const v8bf*)Bs[cur])[(wn * 2 + i) * 64 + lane];
        for (int mi = 0; mi < 2; mi++)
            for (int ni = 0; ni < 2; ni++)
                acc[mi][ni] = MFMA16(a[mi], b[ni], acc[mi][ni]);
        __syncthreads();
    }

    for (int ni = 0; ni < 2; ni++) {
        const int n = col0 + wn * 32 + ni * 16 + r;
        const float bv_ = bias[n];
        for (int mi = 0; mi < 2; mi++) {
            const int mbase = row0 + wm * 32 + mi * 16 + quad * 4;
            for (int i = 0; i < 4; i++)
                y[(size_t)(mbase + i) * 512 + n] = acc[mi][ni][i] + bv_;
        }
    }
}

// ---------------------------------------------------------------------------
extern "C" void kernel_launch(void* const* d_in, const int* in_sizes, int n_in,
                              void* d_out, int out_size, void* d_ws, size_t ws_size,
                              hipStream_t stream)
{
    const float* q    = (const float*)d_in[0];
    const float* k    = (const float*)d_in[1];
    const float* v    = (const float*)d_in[2];
    const int*   mask = (const int*)d_in[3];
    const float* Wq   = (const float*)d_in[4];
    const float* Wk   = (const float*)d_in[5];
    const float* Wv   = (const float*)d_in[6];
    const float* Wo   = (const float*)d_in[7];
    const float* bq   = (const float*)d_in[8];
    const float* bk   = (const float*)d_in[9];
    const float* bv   = (const float*)d_in[10];
    const float* bo   = (const float*)d_in[11];

    // ws (bf16 elems): Q[4M] K[4M] VT[4M] AO[4M] Wb[1M] xb[12M] -> 60.8 MB
    __bf16* ws  = (__bf16*)d_ws;
    __bf16* Qw  = ws;
    __bf16* Kw  = ws + 4194304;
    __bf16* VTw = ws + 8388608;
    __bf16* AOw = ws + 12582912;
    __bf16* Wb  = ws + 16777216;
    __bf16* xbw = ws + 17825792;

    cvt_all<<<dim3(7168), 256, 0, stream>>>(Wq, Wk, Wv, Wo, q, k, v, Wb, xbw);
    qkv_gemm<<<dim3(64, 4, 3), 256, 0, stream>>>(xbw, Wb, bq, bk, bv, Qw, Kw, VTw);
    attn<<<dim3(16, 32), 512, 0, stream>>>(Qw, Kw, VTw, mask, AOw);
    out_gemm<<<dim3(128, 8), 256, 0, stream>>>(AOw, Wb + 786432, bo, (float*)d_out);
}

// Round 19
// 204.360 us; speedup vs baseline: 1.0076x; 1.0076x over previous
//
#include <hip/hip_runtime.h>
#include <hip/hip_bf16.h>

// MHA layer. B=4, S=2048, HID=512, H=8, HD=64. fp32 in/out, bf16 MFMA inside.
// R17: qkv prefetch distance 2 (R16's counted-vmcnt was depth 1 = ~350cy
// cover < L2 latency -> neutral). 3-buf rotation; per iter:
//   {s_waitcnt vmcnt(4) [tile t landed, t+1 in flight] ; s_barrier ;
//    issue DMA(t+2) into buf (t+2)%3 ; compute(t)}
// Every load gets 2 compute phases + barrier (~700-900cy) to land.
// Buffer safety: (t+2)%3 == (t-1)%3 and barrier(t) is after all waves'
// compute(t-1) -> no overwrite race. Prologue stages t0+t1.
// attn: R14 in-block K-split (54-56 measured). out: R15. cvt: R12.

typedef __bf16 v8bf __attribute__((ext_vector_type(8)));
typedef __bf16 v4bf __attribute__((ext_vector_type(4)));
typedef float  v4f  __attribute__((ext_vector_type(4)));

#define MFMA16(a, b, c) __builtin_amdgcn_mfma_f32_16x16x32_bf16((a), (b), (c), 0, 0, 0)

__device__ __forceinline__ void gl16(const __bf16* g, __bf16* l) {
    // DMA 16B/lane global->LDS. LDS dest = wave-uniform base + lane*16.
    __builtin_amdgcn_global_load_lds(
        (const __attribute__((address_space(1))) void*)g,
        (__attribute__((address_space(3))) void*)l, 16, 0, 0);
}

__device__ inline v8bf cvt8(const float* __restrict__ p) {
    const v4f f0 = *(const v4f*)p;
    const v4f f1 = *(const v4f*)(p + 4);
    v8bf r;
    r[0] = (__bf16)f0[0]; r[1] = (__bf16)f0[1]; r[2] = (__bf16)f0[2]; r[3] = (__bf16)f0[3];
    r[4] = (__bf16)f1[0]; r[5] = (__bf16)f1[1]; r[6] = (__bf16)f1[2]; r[7] = (__bf16)f1[3];
    return r;
}

// ---------------------------------------------------------------------------
// K0: fused convert. blocks [0,1024): Wq|Wk|Wv|Wo -> bf16.
//     blocks [1024,7168): xq|xk|xv -> bf16.
// ---------------------------------------------------------------------------
__global__ __launch_bounds__(256) void cvt_all(
    const float* __restrict__ Wq, const float* __restrict__ Wk,
    const float* __restrict__ Wv, const float* __restrict__ Wo,
    const float* __restrict__ xq, const float* __restrict__ xk,
    const float* __restrict__ xv,
    __bf16* __restrict__ Wb, __bf16* __restrict__ xb)
{
    const int bid = blockIdx.x;
    if (bid < 1024) {
        const int idx = (bid * 256 + threadIdx.x) * 4;
        const int w = idx >> 18, off = idx & 262143;
        const float* src = (w == 0) ? Wq : (w == 1) ? Wk : (w == 2) ? Wv : Wo;
        const v4f x = *(const v4f*)(src + off);
        v4bf y;
        y[0] = (__bf16)x[0]; y[1] = (__bf16)x[1]; y[2] = (__bf16)x[2]; y[3] = (__bf16)x[3];
        *(v4bf*)(Wb + idx) = y;
    } else {
        const int idx = ((bid - 1024) * 256 + threadIdx.x) * 8;
        const int w = idx >> 22, off = idx & 4194303;
        const float* src = (w == 0) ? xq : (w == 1) ? xk : xv;
        *(v8bf*)(xb + idx) = cvt8(src + off);
    }
}

// ---------------------------------------------------------------------------
// K1: QKV projection. grid (64, 4, 3), block 256. Tile 128x128, BK=32.
// R17: 3-buffer rotation, counted vmcnt(4), prefetch distance 2 (issue after
// barrier). LDS 48 KB -> 3 blocks/CU.
// ---------------------------------------------------------------------------
__global__ __launch_bounds__(256) void qkv_gemm(
    const __bf16* __restrict__ xb, const __bf16* __restrict__ Wb,
    const float* __restrict__ bq, const float* __restrict__ bk, const float* __restrict__ bv,
    __bf16* __restrict__ Qo, __bf16* __restrict__ Ko, __bf16* __restrict__ VTo)
{
    const int z = blockIdx.z;
    const __bf16* x    = xb + (size_t)z * 4194304;
    const __bf16* W    = Wb + (size_t)z * 262144;
    const float*  bias = (z == 0) ? bq : (z == 1) ? bk : bv;

    const int tid = threadIdx.x, wave = tid >> 6, lane = tid & 63;
    const int quad = lane >> 4, r = lane & 15;
    const int wm = wave >> 1, wn = wave & 1;
    const int row0 = blockIdx.x * 128, col0 = blockIdx.y * 128;

    __shared__ __align__(16) __bf16 As[3][4096];   // 24 KB (3 bufs)
    __shared__ __align__(16) __bf16 Bs[3][4096];   // 24 KB

    // Wave stages segs {2*wave, 2*wave+1} of each plane (4 gl16 per step).
    const __bf16* aG[2];
    const __bf16* bG[2];
    int aOff[2];
    for (int j = 0; j < 2; j++) {
        const int s = wave * 2 + j;
        aG[j] = x + (size_t)(row0 + s * 16 + r) * 512 + quad * 8;
        bG[j] = W + (size_t)(col0 + s * 16 + r) * 512 + quad * 8;
        aOff[j] = s * 512;
    }

    v4f acc[4][4] = {};

    // prologue: stage tiles 0,1 -> bufs 0,1 (8 outstanding)
    for (int j = 0; j < 2; j++) {
        gl16(aG[j], &As[0][aOff[j]]);
        gl16(bG[j], &Bs[0][aOff[j]]);
    }
    for (int j = 0; j < 2; j++) {
        gl16(aG[j] + 32, &As[1][aOff[j]]);
        gl16(bG[j] + 32, &Bs[1][aOff[j]]);
    }

    int cur = 0;
    for (int t = 0; t < 16; t++) {
        // wait: tile t landed (t+1's 4 may stay in flight)
        if (t < 15)
            asm volatile("s_waitcnt vmcnt(4)" ::: "memory");
        else
            asm volatile("s_waitcnt vmcnt(0)" ::: "memory");
        __builtin_amdgcn_s_barrier();               // all waves' tile-t landed
        asm volatile("" ::: "memory");

        if (t < 14) {                               // issue t+2 -> buf (t+2)%3
            const int nb = (cur == 0) ? 2 : cur - 1;    // (t+2)%3
            const int kk = (t + 2) * 32;
            for (int j = 0; j < 2; j++) {
                gl16(aG[j] + kk, &As[nb][aOff[j]]);
                gl16(bG[j] + kk, &Bs[nb][aOff[j]]);
            }
        }

        v8bf a[4], b[4];
        for (int i = 0; i < 4; i++)
            a[i] = ((const v8bf*)As[cur])[(wm * 4 + i) * 64 + lane];
        for (int i = 0; i < 4; i++)
            b[i] = ((const v8bf*)Bs[cur])[(wn * 4 + i) * 64 + lane];
        for (int mi = 0; mi < 4; mi++)
            for (int ni = 0; ni < 4; ni++)
                acc[mi][ni] = MFMA16(a[mi], b[ni], acc[mi][ni]);

        cur = (cur == 2) ? 0 : cur + 1;
    }

    for (int ni = 0; ni < 4; ni++) {
        const int n = col0 + wn * 64 + ni * 16 + r;
        const float bv_ = bias[n];
        const int hh = n >> 6, hd = n & 63;
        for (int mi = 0; mi < 4; mi++) {
            const int mbase = row0 + wm * 64 + mi * 16 + quad * 4;
            const int bb = mbase >> 11, s0 = mbase & 2047;
            if (z == 2) {
                v4bf pk;
                for (int i = 0; i < 4; i++)
                    pk[i] = (__bf16)(acc[mi][ni][i] + bv_);
                *(v4bf*)&VTo[((size_t)((bb * 8 + hh) * 64 + hd)) * 2048 + s0] = pk;
            } else {
                __bf16* dst = (z == 0) ? Qo : Ko;
                for (int i = 0; i < 4; i++)
                    dst[((size_t)((bb * 8 + hh) * 2048 + s0 + i)) * 64 + hd] =
                        (__bf16)(acc[mi][ni][i] + bv_);
            }
        }
    }
}

// ---------------------------------------------------------------------------
// K2: flash attention, IN-BLOCK K-split (R14, measured 54.4-56.5 us).
// grid (16,32), block 512 (8 waves): waves 0-3 K-half 0, waves 4-7 K-half 1,
// same 128 q. Halves merge via LDS epilogue. LDS 72.5 KB -> 2 blocks/CU.
// ---------------------------------------------------------------------------
__global__ __launch_bounds__(512, 4) void attn(
    const __bf16* __restrict__ Q, const __bf16* __restrict__ K,
    const __bf16* __restrict__ VT, const int* __restrict__ mask,
    __bf16* __restrict__ AO)
{
    // Bijective XCD swizzle: each XCD owns 4 heads (K+V 2 MB < 4 MB L2).
    const int id = blockIdx.y * 16 + blockIdx.x;
    const int x8 = id & 7, j = (id >> 3) & 3, qb = id >> 5;
    const int bh = x8 * 4 + j;
    const int b = bh >> 3, h = bh & 7;
    const int tid = threadIdx.x, wave = tid >> 6, lane = tid & 63;
    const int w4 = wave & 3, half = wave >> 2;
    const int ltid = tid & 255;                 // index within the half
    const int quad = lane >> 4, r = lane & 15;
    const int q0 = qb * 128 + w4 * 32;          // 32 q-rows per wave

    const __bf16* Qb = Q  + (size_t)bh * 2048 * 64;
    const __bf16* Kb = K  + (size_t)bh * 2048 * 64 + (size_t)half * 1024 * 64;
    const __bf16* Vb = VT + (size_t)bh * 64 * 2048 + half * 1024;  // col off
    const int*    mb = mask + (size_t)b * 2048;

    __shared__ __align__(16) __bf16 Kls[2][4096];     // 16 KB (per half)
    __shared__ __align__(16) __bf16 Vls[2][4096];     // 16 KB (per half)
    __shared__ __align__(16) float  biasF[2048];      // 8 KB, all keys
    __shared__ __align__(16) __bf16 PF[8][4][64][8];  // 32 KB frag-major P
    __shared__ float osumX[4][32];                    // 512 B

    for (int i = tid; i < 2048; i += 512)
        biasF[i] = (mb[i] != 0) ? 0.f : -1.0e10f;

    // Staging: each half's 256 threads stage its K/V tile (entries e1,e2).
    const int e1 = ltid, e2 = ltid + 256;
    int seg, l, t_, h_, rr, qd;
    seg = e1 >> 6; l = e1 & 63; t_ = seg >> 1; h_ = seg & 1; rr = l & 15; qd = l >> 4;
    const __bf16* kg1 = Kb + (size_t)(16 * t_ + rr) * 64   + h_ * 32 + qd * 8;
    const __bf16* vg1 = Vb + (size_t)(16 * t_ + rr) * 2048 + h_ * 32 + qd * 8;
    seg = e2 >> 6; l = e2 & 63; t_ = seg >> 1; h_ = seg & 1; rr = l & 15; qd = l >> 4;
    const __bf16* kg2 = Kb + (size_t)(16 * t_ + rr) * 64   + h_ * 32 + qd * 8;
    const __bf16* vg2 = Vb + (size_t)(16 * t_ + rr) * 2048 + h_ * 32 + qd * 8;

    // Q fragments (B-operand), two 16-row groups.
    v8bf qf[2][2];
    for (int g = 0; g < 2; g++) {
        qf[g][0] = *(const v8bf*)(Qb + (size_t)(q0 + g * 16 + r) * 64 +      quad * 8);
        qf[g][1] = *(const v8bf*)(Qb + (size_t)(q0 + g * 16 + r) * 64 + 32 + quad * 8);
    }

    v8bf ones;
    for (int i = 0; i < 8; i++) ones[i] = (__bf16)1.0f;

    v4f o[2][4] = {};
    v4f osum[2] = {};

    const float SC = 0.18033688f;   // 0.125 * log2(e)

    // PF write addressing (MFMA C->A layout bridge).
    const int entE = (quad >> 1) * 16 + r;   // tt even
    const int entO = entE + 32;              // tt odd
    const int eoff = (quad & 1) * 4;

    v8bf ks1 = *(const v8bf*)kg1, ks2 = *(const v8bf*)kg2;   // tile 0 -> regs
    v8bf vs1 = *(const v8bf*)vg1, vs2 = *(const v8bf*)vg2;

    for (int t = 0; t < 16; t++) {
        __syncthreads();                        // prev-tile readers done
        ((v8bf*)Kls[half])[e1] = ks1; ((v8bf*)Kls[half])[e2] = ks2;
        ((v8bf*)Vls[half])[e1] = vs1; ((v8bf*)Vls[half])[e2] = vs2;
        __syncthreads();                        // tile t visible
        if (t < 15) {                           // prefetch t+1 -> regs
            const int k0n = (t + 1) * 64;
            ks1 = *(const v8bf*)(kg1 + (size_t)k0n * 64);
            ks2 = *(const v8bf*)(kg2 + (size_t)k0n * 64);
            vs1 = *(const v8bf*)(vg1 + k0n);
            vs2 = *(const v8bf*)(vg2 + k0n);
        }
        const int k0 = t * 64;                  // local key base in half

        // ---- S^T = K.Q^T : each K fragment feeds both q-groups.
        v4f sa[2][4] = {};
        for (int tt = 0; tt < 4; tt++) {
            const v8bf kf0 = ((const v8bf*)Kls[half])[(tt * 2 + 0) * 64 + lane];
            const v8bf kf1 = ((const v8bf*)Kls[half])[(tt * 2 + 1) * 64 + lane];
            sa[0][tt] = MFMA16(kf0, qf[0][0], sa[0][tt]);
            sa[0][tt] = MFMA16(kf1, qf[0][1], sa[0][tt]);
            sa[1][tt] = MFMA16(kf0, qf[1][0], sa[1][tt]);
            sa[1][tt] = MFMA16(kf1, qf[1][1], sa[1][tt]);
        }

        // ---- p = exp2(s*SC + bias); write fragment-major.
        for (int tt = 0; tt < 4; tt++) {
            const v4f bl = *(const v4f*)&biasF[half * 1024 + k0 + tt * 16 + quad * 4];
            const int ent = (tt & 1) ? entO : entE;
            const int pl = tt >> 1;
            for (int g = 0; g < 2; g++) {
                v4bf pk;
                for (int i = 0; i < 4; i++) {
                    const float p = __builtin_amdgcn_exp2f(fmaf(sa[g][tt][i], SC, bl[i]));
                    pk[i] = (__bf16)p;
                }
                *(v4bf*)&PF[wave][g * 2 + pl][ent][eoff] = pk;
            }
        }
        asm volatile("s_waitcnt lgkmcnt(0)" ::: "memory");  // same-wave cross-lane
        v8bf pa[2][2];
        for (int g = 0; g < 2; g++) {
            pa[g][0] = *(const v8bf*)&PF[wave][g * 2 + 0][lane][0];
            pa[g][1] = *(const v8bf*)&PF[wave][g * 2 + 1][lane][0];
        }

        // ---- row sums on the matrix pipe
        osum[0] = MFMA16(pa[0][0], ones, osum[0]);
        osum[0] = MFMA16(pa[0][1], ones, osum[0]);
        osum[1] = MFMA16(pa[1][0], ones, osum[1]);
        osum[1] = MFMA16(pa[1][1], ones, osum[1]);

        // ---- O += P @ V
        for (int t2 = 0; t2 < 4; t2++) {
            const v8bf vf0 = ((const v8bf*)Vls[half])[(t2 * 2 + 0) * 64 + lane];
            const v8bf vf1 = ((const v8bf*)Vls[half])[(t2 * 2 + 1) * 64 + lane];
            o[0][t2] = MFMA16(pa[0][0], vf0, o[0][t2]);
            o[0][t2] = MFMA16(pa[0][1], vf1, o[0][t2]);
            o[1][t2] = MFMA16(pa[1][0], vf0, o[1][t2]);
            o[1][t2] = MFMA16(pa[1][1], vf1, o[1][t2]);
        }
    }

    // ---- epilogue: merge halves via LDS (PF reused as f32 exchange).
    __syncthreads();                            // all waves done reading PF
    float* ex = (float*)&PF[0][0][0][0];
    if (half == 1) {
        for (int g = 0; g < 2; g++) {
            for (int t2 = 0; t2 < 4; t2++)
                for (int i = 0; i < 4; i++)
                    ex[(w4 * 32 + g * 16 + quad * 4 + i) * 64 + t2 * 16 + r] =
                        o[g][t2][i];
            if (r == 0)
                for (int i = 0; i < 4; i++)
                    osumX[w4][g * 16 + quad * 4 + i] = osum[g][i];
        }
    }
    __syncthreads();                            // exchange visible
    if (half == 0) {
        for (int g = 0; g < 2; g++) {
            float inv[4];
            for (int i = 0; i < 4; i++)
                inv[i] = 1.0f / (osum[g][i] + osumX[w4][g * 16 + quad * 4 + i]);
            for (int t2 = 0; t2 < 4; t2++) {
                const int hd = t2 * 16 + r;
                for (int i = 0; i < 4; i++) {
                    const int s = q0 + g * 16 + quad * 4 + i;
                    const float val = o[g][t2][i] +
                        ex[(w4 * 32 + g * 16 + quad * 4 + i) * 64 + hd];
                    AO[((size_t)b * 2048 + s) * 512 + h * 64 + hd] =
                        (__bf16)(val * inv[i]);
                }
            }
        }
    }
}

// ---------------------------------------------------------------------------
// K3: output projection (R15). Tile 64x64, grid (128, 8) = 1024 blocks =
// 4 blocks/CU = 16 waves/CU. BK=32, 2-phase dbuf DMA. Wave computes 32x32.
// ---------------------------------------------------------------------------
__global__ __launch_bounds__(256) void out_gemm(
    const __bf16* __restrict__ Ai, const __bf16* __restrict__ W,
    const float* __restrict__ bias, float* __restrict__ y)
{
    const int tid = threadIdx.x, wave = tid >> 6, lane = tid & 63;
    const int quad = lane >> 4, r = lane & 15;
    const int wm = wave >> 1, wn = wave & 1;
    const int row0 = blockIdx.x * 64, col0 = blockIdx.y * 64;

    __shared__ __align__(16) __bf16 As[2][2048];   // 64x32 per buf
    __shared__ __align__(16) __bf16 Bs[2][2048];   // 64x32 per buf

    const __bf16* aG = Ai + (size_t)(row0 + wave * 16 + r) * 512 + quad * 8;
    const __bf16* bG = W  + (size_t)(col0 + wave * 16 + r) * 512 + quad * 8;
    const int sOff = wave * 512;

    v4f acc[2][2] = {};

    gl16(aG, &As[0][sOff]);
    gl16(bG, &Bs[0][sOff]);
    __syncthreads();

    for (int t = 0; t < 16; t++) {
        const int cur = t & 1;
        if (t < 15) {
            const int kk = (t + 1) * 32;
            gl16(aG + kk, &As[cur ^ 1][sOff]);
            gl16(bG + kk, &Bs[cur ^ 1][sOff]);
        }
        v8bf a[2], b[2];
        for (int i = 0; i < 2; i++)
            a[i] = ((const v8bf*)As[cur])[(wm * 2 + i) * 64 + lane];
        for (int i = 0; i < 2; i++)
            b[i] = ((const v8bf*)Bs[cur])[(wn * 2 + i) * 64 + lane];
        for (int mi = 0; mi < 2; mi++)
            for (int ni = 0; ni < 2; ni++)
                acc[mi][ni] = MFMA16(a[mi], b[ni], acc[mi][ni]);
        __syncthreads();
    }

    for (int ni = 0; ni < 2; ni++) {
        const int n = col0 + wn * 32 + ni * 16 + r;
        const float bv_ = bias[n];
        for (int mi = 0; mi < 2; mi++) {
            const int mbase = row0 + wm * 32 + mi * 16 + quad * 4;
            for (int i = 0; i < 4; i++)
                y[(size_t)(mbase + i) * 512 + n] = acc[mi][ni][i] + bv_;
        }
    }
}

// ---------------------------------------------------------------------------
extern "C" void kernel_launch(void* const* d_in, const int* in_sizes, int n_in,
                              void* d_out, int out_size, void* d_ws, size_t ws_size,
                              hipStream_t stream)
{
    const float* q    = (const float*)d_in[0];
    const float* k    = (const float*)d_in[1];
    const float* v    = (const float*)d_in[2];
    const int*   mask = (const int*)d_in[3];
    const float* Wq   = (const float*)d_in[4];
    const float* Wk   = (const float*)d_in[5];
    const float* Wv   = (const float*)d_in[6];
    const float* Wo   = (const float*)d_in[7];
    const float* bq   = (const float*)d_in[8];
    const float* bk   = (const float*)d_in[9];
    const float* bv   = (const float*)d_in[10];
    const float* bo   = (const float*)d_in[11];

    // ws (bf16 elems): Q[4M] K[4M] VT[4M] AO[4M] Wb[1M] xb[12M] -> 60.8 MB
    __bf16* ws  = (__bf16*)d_ws;
    __bf16* Qw  = ws;
    __bf16* Kw  = ws + 4194304;
    __bf16* VTw = ws + 8388608;
    __bf16* AOw = ws + 12582912;
    __bf16* Wb  = ws + 16777216;
    __bf16* xbw = ws + 17825792;

    cvt_all<<<dim3(7168), 256, 0, stream>>>(Wq, Wk, Wv, Wo, q, k, v, Wb, xbw);
    qkv_gemm<<<dim3(64, 4, 3), 256, 0, stream>>>(xbw, Wb, bq, bk, bv, Qw, Kw, VTw);
    attn<<<dim3(16, 32), 512, 0, stream>>>(Qw, Kw, VTw, mask, AOw);
    out_gemm<<<dim3(128, 8), 256, 0, stream>>>(AOw, Wb + 786432, bo, (float*)d_out);
}

// Round 21
// 200.683 us; speedup vs baseline: 1.0260x; 1.0183x over previous
//
#include <hip/hip_runtime.h>
#include <hip/hip_bf16.h>

// MHA layer. B=4, S=2048, HID=512, H=8, HD=64. fp32 in/out, bf16 MFMA inside.
// R18 (lock-in resubmit after broker timeout; = R14 config, the measured
// optimum at 203.85 us):
//  * attn: in-block K-split. 512-thread blocks (8 waves): waves 0-3 K-half 0,
//    waves 4-7 K-half 1 for the same 128 q-rows; halves merge via LDS
//    epilogue. 2 blocks/CU = 4 waves/SIMD. Measured 54.4-55.2 us.
//  * qkv: bf16-A 2-phase dbuf DMA pipeline (counted-vmcnt variants R16/R17
//    measured neutral; this is the simplest of the equal-fast family).
//  * out_gemm: 64x128 2-phase dbuf (R15's 64x64 retile measured neutral).
//  * cvt_all: fused W+x conversion.
// Session: 238.5 -> 203.9 us.

typedef __bf16 v8bf __attribute__((ext_vector_type(8)));
typedef __bf16 v4bf __attribute__((ext_vector_type(4)));
typedef float  v4f  __attribute__((ext_vector_type(4)));

#define MFMA16(a, b, c) __builtin_amdgcn_mfma_f32_16x16x32_bf16((a), (b), (c), 0, 0, 0)

__device__ __forceinline__ void gl16(const __bf16* g, __bf16* l) {
    // DMA 16B/lane global->LDS. LDS dest = wave-uniform base + lane*16.
    __builtin_amdgcn_global_load_lds(
        (const __attribute__((address_space(1))) void*)g,
        (__attribute__((address_space(3))) void*)l, 16, 0, 0);
}

__device__ inline v8bf cvt8(const float* __restrict__ p) {
    const v4f f0 = *(const v4f*)p;
    const v4f f1 = *(const v4f*)(p + 4);
    v8bf r;
    r[0] = (__bf16)f0[0]; r[1] = (__bf16)f0[1]; r[2] = (__bf16)f0[2]; r[3] = (__bf16)f0[3];
    r[4] = (__bf16)f1[0]; r[5] = (__bf16)f1[1]; r[6] = (__bf16)f1[2]; r[7] = (__bf16)f1[3];
    return r;
}

// ---------------------------------------------------------------------------
// K0: fused convert. blocks [0,1024): Wq|Wk|Wv|Wo -> bf16.
//     blocks [1024,7168): xq|xk|xv -> bf16.
// ---------------------------------------------------------------------------
__global__ __launch_bounds__(256) void cvt_all(
    const float* __restrict__ Wq, const float* __restrict__ Wk,
    const float* __restrict__ Wv, const float* __restrict__ Wo,
    const float* __restrict__ xq, const float* __restrict__ xk,
    const float* __restrict__ xv,
    __bf16* __restrict__ Wb, __bf16* __restrict__ xb)
{
    const int bid = blockIdx.x;
    if (bid < 1024) {
        const int idx = (bid * 256 + threadIdx.x) * 4;
        const int w = idx >> 18, off = idx & 262143;
        const float* src = (w == 0) ? Wq : (w == 1) ? Wk : (w == 2) ? Wv : Wo;
        const v4f x = *(const v4f*)(src + off);
        v4bf y;
        y[0] = (__bf16)x[0]; y[1] = (__bf16)x[1]; y[2] = (__bf16)x[2]; y[3] = (__bf16)x[3];
        *(v4bf*)(Wb + idx) = y;
    } else {
        const int idx = ((bid - 1024) * 256 + threadIdx.x) * 8;
        const int w = idx >> 22, off = idx & 4194303;
        const float* src = (w == 0) ? xq : (w == 1) ? xk : xv;
        *(v8bf*)(xb + idx) = cvt8(src + off);
    }
}

// ---------------------------------------------------------------------------
// K1: QKV projection. grid (64, 4, 3), block 256. Tile 128x128, BK=32,
// 2-phase dbuf DMA pipeline: stage(t+1 -> buf^1); compute(buf); barrier.
// ---------------------------------------------------------------------------
__global__ __launch_bounds__(256) void qkv_gemm(
    const __bf16* __restrict__ xb, const __bf16* __restrict__ Wb,
    const float* __restrict__ bq, const float* __restrict__ bk, const float* __restrict__ bv,
    __bf16* __restrict__ Qo, __bf16* __restrict__ Ko, __bf16* __restrict__ VTo)
{
    const int z = blockIdx.z;
    const __bf16* x    = xb + (size_t)z * 4194304;
    const __bf16* W    = Wb + (size_t)z * 262144;
    const float*  bias = (z == 0) ? bq : (z == 1) ? bk : bv;

    const int tid = threadIdx.x, wave = tid >> 6, lane = tid & 63;
    const int quad = lane >> 4, r = lane & 15;
    const int wm = wave >> 1, wn = wave & 1;
    const int row0 = blockIdx.x * 128, col0 = blockIdx.y * 128;

    __shared__ __align__(16) __bf16 As[2][4096];
    __shared__ __align__(16) __bf16 Bs[2][4096];

    const __bf16* aG[2];
    const __bf16* bG[2];
    int aOff[2];
    for (int j = 0; j < 2; j++) {
        const int s = wave * 2 + j;
        aG[j] = x + (size_t)(row0 + s * 16 + r) * 512 + quad * 8;
        bG[j] = W + (size_t)(col0 + s * 16 + r) * 512 + quad * 8;
        aOff[j] = s * 512;
    }

    v4f acc[4][4] = {};

    for (int j = 0; j < 2; j++) {
        gl16(aG[j], &As[0][aOff[j]]);
        gl16(bG[j], &Bs[0][aOff[j]]);
    }
    __syncthreads();

    for (int t = 0; t < 16; t++) {
        const int cur = t & 1;
        if (t < 15) {
            const int kk = (t + 1) * 32;
            for (int j = 0; j < 2; j++) {
                gl16(aG[j] + kk, &As[cur ^ 1][aOff[j]]);
                gl16(bG[j] + kk, &Bs[cur ^ 1][aOff[j]]);
            }
        }
        v8bf a[4], b[4];
        for (int i = 0; i < 4; i++)
            a[i] = ((const v8bf*)As[cur])[(wm * 4 + i) * 64 + lane];
        for (int i = 0; i < 4; i++)
            b[i] = ((const v8bf*)Bs[cur])[(wn * 4 + i) * 64 + lane];
        for (int mi = 0; mi < 4; mi++)
            for (int ni = 0; ni < 4; ni++)
                acc[mi][ni] = MFMA16(a[mi], b[ni], acc[mi][ni]);
        __syncthreads();
    }

    for (int ni = 0; ni < 4; ni++) {
        const int n = col0 + wn * 64 + ni * 16 + r;
        const float bv_ = bias[n];
        const int hh = n >> 6, hd = n & 63;
        for (int mi = 0; mi < 4; mi++) {
            const int mbase = row0 + wm * 64 + mi * 16 + quad * 4;
            const int bb = mbase >> 11, s0 = mbase & 2047;
            if (z == 2) {
                v4bf pk;
                for (int i = 0; i < 4; i++)
                    pk[i] = (__bf16)(acc[mi][ni][i] + bv_);
                *(v4bf*)&VTo[((size_t)((bb * 8 + hh) * 64 + hd)) * 2048 + s0] = pk;
            } else {
                __bf16* dst = (z == 0) ? Qo : Ko;
                for (int i = 0; i < 4; i++)
                    dst[((size_t)((bb * 8 + hh) * 2048 + s0 + i)) * 64 + hd] =
                        (__bf16)(acc[mi][ni][i] + bv_);
            }
        }
    }
}

// ---------------------------------------------------------------------------
// K2: flash attention, IN-BLOCK K-split. grid (16, 32), block 512 (8 waves).
// Waves 0-3 (half 0) and 4-7 (half 1) each process 1024 keys for the same
// 128 q-rows; 16 tiles each, 2-barrier loop with register prefetch. Halves
// merge via LDS epilogue (PF reused as f32 exchange). LDS 72.5 KB ->
// 2 blocks/CU = 4 waves/SIMD. Measured 54.4-55.2 us.
// ---------------------------------------------------------------------------
__global__ __launch_bounds__(512, 4) void attn(
    const __bf16* __restrict__ Q, const __bf16* __restrict__ K,
    const __bf16* __restrict__ VT, const int* __restrict__ mask,
    __bf16* __restrict__ AO)
{
    // Bijective XCD swizzle: each XCD owns 4 heads (K+V 2 MB < 4 MB L2).
    const int id = blockIdx.y * 16 + blockIdx.x;
    const int x8 = id & 7, j = (id >> 3) & 3, qb = id >> 5;
    const int bh = x8 * 4 + j;
    const int b = bh >> 3, h = bh & 7;
    const int tid = threadIdx.x, wave = tid >> 6, lane = tid & 63;
    const int w4 = wave & 3, half = wave >> 2;
    const int ltid = tid & 255;                 // index within the half
    const int quad = lane >> 4, r = lane & 15;
    const int q0 = qb * 128 + w4 * 32;          // 32 q-rows per wave

    const __bf16* Qb = Q  + (size_t)bh * 2048 * 64;
    const __bf16* Kb = K  + (size_t)bh * 2048 * 64 + (size_t)half * 1024 * 64;
    const __bf16* Vb = VT + (size_t)bh * 64 * 2048 + half * 1024;  // col off
    const int*    mb = mask + (size_t)b * 2048;

    __shared__ __align__(16) __bf16 Kls[2][4096];     // 16 KB (per half)
    __shared__ __align__(16) __bf16 Vls[2][4096];     // 16 KB (per half)
    __shared__ __align__(16) float  biasF[2048];      // 8 KB, all keys
    __shared__ __align__(16) __bf16 PF[8][4][64][8];  // 32 KB frag-major P
    __shared__ float osumX[4][32];                    // 512 B

    for (int i = tid; i < 2048; i += 512)
        biasF[i] = (mb[i] != 0) ? 0.f : -1.0e10f;

    // Staging: each half's 256 threads stage its K/V tile (entries e1,e2).
    const int e1 = ltid, e2 = ltid + 256;
    int seg, l, t_, h_, rr, qd;
    seg = e1 >> 6; l = e1 & 63; t_ = seg >> 1; h_ = seg & 1; rr = l & 15; qd = l >> 4;
    const __bf16* kg1 = Kb + (size_t)(16 * t_ + rr) * 64   + h_ * 32 + qd * 8;
    const __bf16* vg1 = Vb + (size_t)(16 * t_ + rr) * 2048 + h_ * 32 + qd * 8;
    seg = e2 >> 6; l = e2 & 63; t_ = seg >> 1; h_ = seg & 1; rr = l & 15; qd = l >> 4;
    const __bf16* kg2 = Kb + (size_t)(16 * t_ + rr) * 64   + h_ * 32 + qd * 8;
    const __bf16* vg2 = Vb + (size_t)(16 * t_ + rr) * 2048 + h_ * 32 + qd * 8;

    // Q fragments (B-operand), two 16-row groups.
    v8bf qf[2][2];
    for (int g = 0; g < 2; g++) {
        qf[g][0] = *(const v8bf*)(Qb + (size_t)(q0 + g * 16 + r) * 64 +      quad * 8);
        qf[g][1] = *(const v8bf*)(Qb + (size_t)(q0 + g * 16 + r) * 64 + 32 + quad * 8);
    }

    v8bf ones;
    for (int i = 0; i < 8; i++) ones[i] = (__bf16)1.0f;

    v4f o[2][4] = {};
    v4f osum[2] = {};

    const float SC = 0.18033688f;   // 0.125 * log2(e)

    // PF write addressing (MFMA C->A layout bridge).
    const int entE = (quad >> 1) * 16 + r;   // tt even
    const int entO = entE + 32;              // tt odd
    const int eoff = (quad & 1) * 4;

    v8bf ks1 = *(const v8bf*)kg1, ks2 = *(const v8bf*)kg2;   // tile 0 -> regs
    v8bf vs1 = *(const v8bf*)vg1, vs2 = *(const v8bf*)vg2;

    for (int t = 0; t < 16; t++) {
        __syncthreads();                        // prev-tile readers done
        ((v8bf*)Kls[half])[e1] = ks1; ((v8bf*)Kls[half])[e2] = ks2;
        ((v8bf*)Vls[half])[e1] = vs1; ((v8bf*)Vls[half])[e2] = vs2;
        __syncthreads();                        // tile t visible
        if (t < 15) {                           // prefetch t+1 -> regs
            const int k0n = (t + 1) * 64;
            ks1 = *(const v8bf*)(kg1 + (size_t)k0n * 64);
            ks2 = *(const v8bf*)(kg2 + (size_t)k0n * 64);
            vs1 = *(const v8bf*)(vg1 + k0n);
            vs2 = *(const v8bf*)(vg2 + k0n);
        }
        const int k0 = t * 64;                  // local key base in half

        // ---- S^T = K.Q^T : each K fragment feeds both q-groups.
        v4f sa[2][4] = {};
        for (int tt = 0; tt < 4; tt++) {
            const v8bf kf0 = ((const v8bf*)Kls[half])[(tt * 2 + 0) * 64 + lane];
            const v8bf kf1 = ((const v8bf*)Kls[half])[(tt * 2 + 1) * 64 + lane];
            sa[0][tt] = MFMA16(kf0, qf[0][0], sa[0][tt]);
            sa[0][tt] = MFMA16(kf1, qf[0][1], sa[0][tt]);
            sa[1][tt] = MFMA16(kf0, qf[1][0], sa[1][tt]);
            sa[1][tt] = MFMA16(kf1, qf[1][1], sa[1][tt]);
        }

        // ---- p = exp2(s*SC + bias); write fragment-major.
        for (int tt = 0; tt < 4; tt++) {
            const v4f bl = *(const v4f*)&biasF[half * 1024 + k0 + tt * 16 + quad * 4];
            const int ent = (tt & 1) ? entO : entE;
            const int pl = tt >> 1;
            for (int g = 0; g < 2; g++) {
                v4bf pk;
                for (int i = 0; i < 4; i++) {
                    const float p = __builtin_amdgcn_exp2f(fmaf(sa[g][tt][i], SC, bl[i]));
                    pk[i] = (__bf16)p;
                }
                *(v4bf*)&PF[wave][g * 2 + pl][ent][eoff] = pk;
            }
        }
        asm volatile("s_waitcnt lgkmcnt(0)" ::: "memory");  // same-wave cross-lane
        v8bf pa[2][2];
        for (int g = 0; g < 2; g++) {
            pa[g][0] = *(const v8bf*)&PF[wave][g * 2 + 0][lane][0];
            pa[g][1] = *(const v8bf*)&PF[wave][g * 2 + 1][lane][0];
        }

        // ---- row sums on the matrix pipe
        osum[0] = MFMA16(pa[0][0], ones, osum[0]);
        osum[0] = MFMA16(pa[0][1], ones, osum[0]);
        osum[1] = MFMA16(pa[1][0], ones, osum[1]);
        osum[1] = MFMA16(pa[1][1], ones, osum[1]);

        // ---- O += P @ V
        for (int t2 = 0; t2 < 4; t2++) {
            const v8bf vf0 = ((const v8bf*)Vls[half])[(t2 * 2 + 0) * 64 + lane];
            const v8bf vf1 = ((const v8bf*)Vls[half])[(t2 * 2 + 1) * 64 + lane];
            o[0][t2] = MFMA16(pa[0][0], vf0, o[0][t2]);
            o[0][t2] = MFMA16(pa[0][1], vf1, o[0][t2]);
            o[1][t2] = MFMA16(pa[1][0], vf0, o[1][t2]);
            o[1][t2] = MFMA16(pa[1][1], vf1, o[1][t2]);
        }
    }

    // ---- epilogue: merge halves via LDS (PF reused as f32 exchange).
    __syncthreads();                            // all waves done reading PF
    float* ex = (float*)&PF[0][0][0][0];
    if (half == 1) {
        for (int g = 0; g < 2; g++) {
            for (int t2 = 0; t2 < 4; t2++)
                for (int i = 0; i < 4; i++)
                    ex[(w4 * 32 + g * 16 + quad * 4 + i) * 64 + t2 * 16 + r] =
                        o[g][t2][i];
            if (r == 0)
                for (int i = 0; i < 4; i++)
                    osumX[w4][g * 16 + quad * 4 + i] = osum[g][i];
        }
    }
    __syncthreads();                            // exchange visible
    if (half == 0) {
        for (int g = 0; g < 2; g++) {
            float inv[4];
            for (int i = 0; i < 4; i++)
                inv[i] = 1.0f / (osum[g][i] + osumX[w4][g * 16 + quad * 4 + i]);
            for (int t2 = 0; t2 < 4; t2++) {
                const int hd = t2 * 16 + r;
                for (int i = 0; i < 4; i++) {
                    const int s = q0 + g * 16 + quad * 4 + i;
                    const float val = o[g][t2][i] +
                        ex[(w4 * 32 + g * 16 + quad * 4 + i) * 64 + hd];
                    AO[((size_t)b * 2048 + s) * 512 + h * 64 + hd] =
                        (__bf16)(val * inv[i]);
                }
            }
        }
    }
}

// ---------------------------------------------------------------------------
// K3: output projection. Tile 64x128, BK=32, 2-phase dbuf DMA pipeline.
// grid (128, 4) = 512 blocks. Wave computes 32x64. LDS 24 KB.
// ---------------------------------------------------------------------------
__global__ __launch_bounds__(256) void out_gemm(
    const __bf16* __restrict__ Ai, const __bf16* __restrict__ W,
    const float* __restrict__ bias, float* __restrict__ y)
{
    const int tid = threadIdx.x, wave = tid >> 6, lane = tid & 63;
    const int quad = lane >> 4, r = lane & 15;
    const int wm = wave >> 1, wn = wave & 1;
    const int row0 = blockIdx.x * 64, col0 = blockIdx.y * 128;

    __shared__ __align__(16) __bf16 As[2][2048];
    __shared__ __align__(16) __bf16 Bs[2][4096];

    const __bf16* aG = Ai + (size_t)(row0 + wave * 16 + r) * 512 + quad * 8;
    const int aOff = wave * 512;
    const __bf16* bG[2];
    int bOff[2];
    for (int j = 0; j < 2; j++) {
        const int s = wave * 2 + j;
        bG[j] = W + (size_t)(col0 + s * 16 + r) * 512 + quad * 8;
        bOff[j] = s * 512;
    }

    v4f acc[2][4] = {};

    gl16(aG, &As[0][aOff]);
    gl16(bG[0], &Bs[0][bOff[0]]);
    gl16(bG[1], &Bs[0][bOff[1]]);
    __syncthreads();

    for (int t = 0; t < 16; t++) {
        const int cur = t & 1;
        if (t < 15) {
            const int kk = (t + 1) * 32;
            gl16(aG + kk, &As[cur ^ 1][aOff]);
            gl16(bG[0] + kk, &Bs[cur ^ 1][bOff[0]]);
            gl16(bG[1] + kk, &Bs[cur ^ 1][bOff[1]]);
        }
        v8bf a[2], b[4];
        for (int i = 0; i < 2; i++)
            a[i] = ((const v8bf*)As[cur])[(wm * 2 + i) * 64 + lane];
        for (int i = 0; i < 4; i++)
            b[i] = ((const v8bf*)Bs[cur])[(wn * 4 + i) * 64 + lane];
        for (int mi = 0; mi < 2; mi++)
            for (int ni = 0; ni < 4; ni++)
                acc[mi][ni] = MFMA16(a[mi], b[ni], acc[mi][ni]);
        __syncthreads();
    }

    for (int ni = 0; ni < 4; ni++) {
        const int n = col0 + wn * 64 + ni * 16 + r;
        const float bv_ = bias[n];
        for (int mi = 0; mi < 2; mi++) {
            const int mbase = row0 + wm * 32 + mi * 16 + quad * 4;
            for (int i = 0; i < 4; i++)
                y[(size_t)(mbase + i) * 512 + n] = acc[mi][ni][i] + bv_;
        }
    }
}

// ---------------------------------------------------------------------------
extern "C" void kernel_launch(void* const* d_in, const int* in_sizes, int n_in,
                              void* d_out, int out_size, void* d_ws, size_t ws_size,
                              hipStream_t stream)
{
    const float* q    = (const float*)d_in[0];
    const float* k    = (const float*)d_in[1];
    const float* v    = (const float*)d_in[2];
    const int*   mask = (const int*)d_in[3];
    const float* Wq   = (const float*)d_in[4];
    const float* Wk   = (const float*)d_in[5];
    const float* Wv   = (const float*)d_in[6];
    const float* Wo   = (const float*)d_in[7];
    const float* bq   = (const float*)d_in[8];
    const float* bk   = (const float*)d_in[9];
    const float* bv   = (const float*)d_in[10];
    const float* bo   = (const float*)d_in[11];

    // ws (bf16 elems): Q[4M] K[4M] VT[4M] AO[4M] Wb[1M] xb[12M] -> 60.8 MB
    __bf16* ws  = (__bf16*)d_ws;
    __bf16* Qw  = ws;
    __bf16* Kw  = ws + 4194304;
    __bf16* VTw = ws + 8388608;
    __bf16* AOw = ws + 12582912;
    __bf16* Wb  = ws + 16777216;
    __bf16* xbw = ws + 17825792;

    cvt_all<<<dim3(7168), 256, 0, stream>>>(Wq, Wk, Wv, Wo, q, k, v, Wb, xbw);
    qkv_gemm<<<dim3(64, 4, 3), 256, 0, stream>>>(xbw, Wb, bq, bk, bv, Qw, Kw, VTw);
    attn<<<dim3(16, 32), 512, 0, stream>>>(Qw, Kw, VTw, mask, AOw);
    out_gemm<<<dim3(128, 4), 256, 0, stream>>>(AOw, Wb + 786432, bo, (float*)d_out);
}